// Round 15
// baseline (653.563 us; speedup 1.0000x reference)
//
#include <hip/hip_runtime.h>

#define TOK    16384
#define HD     1024
#define ID     4096
#define NE     4
#define MAXMT  131   // worst-case M-tiles at BM=128
#define MAXMT2 67    // worst-case M-tiles at BM=256 (gemm1)
#define NKT    (HD / 64)   // 16 K-tiles for gemm1
#define NT1    (MAXMT2 * 32)   // gemm1 tile-id bound
#define NT2    (MAXMT * 16)    // gemm2 tile-id bound (BN=64 -> 16 ny)

typedef __attribute__((ext_vector_type(4))) float f32x4;
typedef __attribute__((ext_vector_type(8))) short bf16x8;
typedef unsigned int u32;

static __device__ __forceinline__ unsigned short f2bf(float f) {
  unsigned u = __float_as_uint(f);
  u += 0x7FFFu + ((u >> 16) & 1u);   // RNE
  return (unsigned short)(u >> 16);
}

static __device__ __forceinline__ void gl16(const void* g, void* l) {
  __builtin_amdgcn_global_load_lds((const __attribute__((address_space(1))) u32*)g,
                                   (__attribute__((address_space(3))) u32*)l, 16, 0, 0);
}

static __device__ __forceinline__ void barx() {
  asm volatile("" ::: "memory");
  __builtin_amdgcn_s_barrier();
  asm volatile("" ::: "memory");
}

// ---------------- routing (+ persistent-counter reset each call) ----------------
__global__ void k_route0(const int* __restrict__ ids, int* __restrict__ meta,
                         int* __restrict__ ctrs) {
  __shared__ int cnt[4];
  int t = threadIdx.x;
  if (t < 4) cnt[t] = 0;
  __syncthreads();
  int l0 = 0, l1 = 0, l2 = 0, l3 = 0;
  for (int i = t; i < TOK; i += 256) {
    int e = ids[i] & 3;
    l0 += (e == 0); l1 += (e == 1); l2 += (e == 2); l3 += (e == 3);
  }
  atomicAdd(&cnt[0], l0); atomicAdd(&cnt[1], l1);
  atomicAdd(&cnt[2], l2); atomicAdd(&cnt[3], l3);
  __syncthreads();
  if (t == 0) {
    int o = 0;
    for (int e = 0; e < 4; ++e) { meta[e] = o; meta[8 + e] = o; o += cnt[e]; }
    meta[4] = o;
    ctrs[0] = 0;   // gemm1 work-steal counter
  }
}

__global__ void k_route1(const int* __restrict__ ids, int* __restrict__ meta,
                         int* __restrict__ perm) {
  int i = blockIdx.x * 256 + threadIdx.x;
  if (i < TOK) {
    int e = ids[i] & 3;
    int s = atomicAdd(&meta[8 + e], 1);
    perm[s] = i;
  }
}

// ------- fused pre-pass: z 0..11 weight transposes, z 12..19 hid f32->bf16 -------
__global__ void k_pre(const float* __restrict__ gw, const float* __restrict__ uw,
                      const float* __restrict__ dw, const float* __restrict__ hs,
                      unsigned short* __restrict__ gT, unsigned short* __restrict__ uT,
                      unsigned short* __restrict__ dT, unsigned short* __restrict__ hid) {
  int z = blockIdx.y;
  int t = threadIdx.x;
  if (z >= 12) {
    int i = ((z - 12) * 1024 + blockIdx.x) * 256 + t;   // vec8 index
    const f32x4* p = (const f32x4*)(hs + ((size_t)i << 3));
    f32x4 a = p[0], b = p[1];
    union { unsigned short u[8]; uint4 q; } o;
    o.u[0] = f2bf(a.x); o.u[1] = f2bf(a.y); o.u[2] = f2bf(a.z); o.u[3] = f2bf(a.w);
    o.u[4] = f2bf(b.x); o.u[5] = f2bf(b.y); o.u[6] = f2bf(b.z); o.u[7] = f2bf(b.w);
    *(uint4*)(hid + ((size_t)i << 3)) = o.q;
    return;
  }
  __shared__ float tile[64][65];
  const float* s; unsigned short* d; int R, C, lg;
  if (z < 8) {
    R = HD; C = ID; lg = 6;
    int m = z & 3;
    if (z < 4) { s = gw + (size_t)m * R * C; d = gT + (size_t)m * R * C; }
    else       { s = uw + (size_t)m * R * C; d = uT + (size_t)m * R * C; }
  } else {
    R = ID; C = HD; lg = 4;
    int m = z - 8;
    s = dw + (size_t)m * R * C; d = dT + (size_t)m * R * C;
  }
  int bx = blockIdx.x;
  int tx = bx & ((1 << lg) - 1), ty = bx >> lg;
  int r0 = ty << 6, c0 = tx << 6;
  int lr = t >> 4, lc = (t & 15) << 2;
  #pragma unroll
  for (int it = 0; it < 4; ++it) {
    int r = lr + (it << 4);
    f32x4 v = *(const f32x4*)(s + (size_t)(r0 + r) * C + c0 + lc);
    tile[r][lc] = v.x; tile[r][lc + 1] = v.y; tile[r][lc + 2] = v.z; tile[r][lc + 3] = v.w;
  }
  __syncthreads();
  int c = t >> 2, rb = (t & 3) << 4;
  union { unsigned short u[16]; uint4 q[2]; } o;
  #pragma unroll
  for (int j = 0; j < 16; ++j) o.u[j] = f2bf(tile[rb + j][c]);
  uint4* dp = (uint4*)(d + (size_t)(c0 + c) * R + r0 + rb);
  dp[0] = o.q[0]; dp[1] = o.q[1];
}

// ---------------- GEMM1: round-3 body in persistent work-steal loop (round-13/14) ----
#define MFMA16 __builtin_amdgcn_mfma_f32_16x16x32_bf16

#define RD_A(MH, KX, D) { _Pragma("unroll") for (int m = 0; m < 4; ++m) \
  fa[m] = *(const bf16x8*)(smem + (D) + ((offA[m] + (MH) * 8192) ^ ((KX) << 6))); }
#define RD_B(KX, D) { _Pragma("unroll") for (int n = 0; n < 4; ++n) \
  fb[n] = *(const bf16x8*)(smem + (D) + (offB[n] ^ ((KX) << 6))); }
#define STG_A(HH, TILE, D) { _Pragma("unroll") for (int j = (HH) * 2; j < (HH) * 2 + 2; ++j) \
  gl16(srcA[j] + (TILE) * 64, smem + (D) + dstA[j]); }
#define STG_B(HH, TILE, D) { _Pragma("unroll") for (int j = (HH) * 2; j < (HH) * 2 + 2; ++j) \
  gl16(srcB[j] + (TILE) * 64, smem + (D) + dstB[j]); }
#define PH_TAIL(MH) barx(); \
  asm volatile("s_waitcnt lgkmcnt(0)" ::: "memory"); \
  __builtin_amdgcn_sched_barrier(0); \
  __builtin_amdgcn_s_setprio(1); \
  { _Pragma("unroll") for (int m = 0; m < 4; ++m) \
    _Pragma("unroll") for (int n = 0; n < 4; ++n) \
      acc[(MH) * 4 + m][n] = MFMA16(fa[m], fb[n], acc[(MH) * 4 + m][n], 0, 0, 0); } \
  __builtin_amdgcn_s_setprio(0)

__global__ __launch_bounds__(512, 2) void k_gemm1(
    const unsigned short* __restrict__ hid,   // [TOK][HD] bf16
    const unsigned short* __restrict__ gT,    // [NE][ID][HD] bf16
    const unsigned short* __restrict__ uT,    // [NE][ID][HD] bf16
    const int* __restrict__ meta,
    const int* __restrict__ perm,
    unsigned short* __restrict__ act,         // [TOK][ID] bf16, slot-ordered
    int* ctr) {
  extern __shared__ __align__(16) char smem[];   // 2 dbuf x (A 32K | B 32K)
  __shared__ int s_t;
  int offs[5];
  #pragma unroll
  for (int i = 0; i < 5; ++i) offs[i] = meta[i];
  int tid = threadIdx.x, lane = tid & 63, wid = tid >> 6;

  // ---- tile-invariant setup ----
  int rsub = lane >> 3;                       // 0..7
  int ke = ((lane & 7) ^ rsub) << 3;          // element offset within 64-wide k-chunk
  int dstA[4], dstB[4];
  #pragma unroll
  for (int j = 0; j < 4; ++j) {
    dstA[j] = j * 8192 + wid * 1024;
    dstB[j] = 32768 + j * 8192 + wid * 1024;
  }
  int wm = wid >> 2, wn = wid & 3;            // 2M x 4N waves
  int r16 = lane & 15, kg = lane >> 4;
  int offA[4], offB[4];
  #pragma unroll
  for (int m = 0; m < 4; ++m) {
    int row = wm * 128 + m * 16 + r16;
    offA[m] = row * 128 + ((kg << 4) ^ ((row & 7) << 4));
  }
  #pragma unroll
  for (int n = 0; n < 4; ++n) {
    int row = wn * 64 + n * 16 + r16;
    offB[n] = 32768 + row * 128 + ((kg << 4) ^ ((row & 7) << 4));
  }
  bf16x8 fa[4], fb[4];

  for (;;) {
    __syncthreads();                          // broadcast slot + cross-tile LDS fence
    if (tid == 0) s_t = atomicAdd(ctr, 1);
    __syncthreads();
    int tt = s_t;
    if (tt >= NT1) break;
    int mt = tt >> 5;
    int ny = tt & 31;
    int e = -1, mloc = 0, base = 0;
    #pragma unroll
    for (int ee = 0; ee < 4; ++ee) {
      int tiles = (offs[ee + 1] - offs[ee] + 255) >> 8;
      if (e < 0 && mt < base + tiles) { e = ee; mloc = mt - base; }
      base += tiles;
    }
    if (e < 0) continue;
    int slot0 = offs[e] + (mloc << 8);
    int send = offs[e + 1];
    int n0 = ny << 7;

    const unsigned short* srcA[4];
    const unsigned short* srcB[4];
    const unsigned short* gb = gT + (size_t)e * ID * HD;
    const unsigned short* ub = uT + (size_t)e * ID * HD;
    #pragma unroll
    for (int j = 0; j < 4; ++j) {
      int r = j * 64 + wid * 8 + rsub;        // A tile row 0..255
      int slot = slot0 + r;
      int pr = perm[slot < send ? slot : slot0];
      srcA[j] = hid + (size_t)pr * HD + ke;
      int s = r >> 4;                         // subtile: even->G, odd->U
      int grow = n0 + ((s >> 1) << 4) + (r & 15);
      srcB[j] = ((s & 1) ? ub : gb) + (size_t)grow * HD + ke;
    }

    f32x4 acc[8][4];
    #pragma unroll
    for (int m = 0; m < 8; ++m)
      #pragma unroll
      for (int n = 0; n < 4; ++n) acc[m][n] = (f32x4){0.f, 0.f, 0.f, 0.f};

    STG_B(0, 0, 0);
    STG_A(0, 0, 0); STG_A(1, 0, 0);
    STG_B(1, 0, 0);
    STG_B(0, 1, 65536);
    asm volatile("s_waitcnt vmcnt(2)" ::: "memory");
    barx();

    #pragma unroll 1
    for (int i = 0; i < NKT / 2 - 1; ++i) {
      int t1 = 2 * i + 1, t2 = 2 * i + 2, t3 = 2 * i + 3;
      RD_A(0, 0, 0); RD_B(0, 0);
      STG_B(1, t1, 65536);
      PH_TAIL(0); barx();
      RD_A(1, 0, 0);
      STG_A(0, t1, 65536); STG_A(1, t1, 65536);
      PH_TAIL(1); barx();
      RD_A(0, 1, 0); RD_B(1, 0);
      PH_TAIL(0); barx();
      RD_A(1, 1, 0);
      STG_B(0, t2, 0);
      PH_TAIL(1);
      asm volatile("s_waitcnt vmcnt(2)" ::: "memory");
      barx();
      RD_A(0, 0, 65536); RD_B(0, 65536);
      STG_A(0, t2, 0); STG_A(1, t2, 0);
      PH_TAIL(0); barx();
      RD_A(1, 0, 65536);
      STG_B(1, t2, 0);
      PH_TAIL(1); barx();
      RD_A(0, 1, 65536); RD_B(1, 65536);
      PH_TAIL(0); barx();
      RD_A(1, 1, 65536);
      STG_B(0, t3, 65536);
      PH_TAIL(1);
      asm volatile("s_waitcnt vmcnt(2)" ::: "memory");
      barx();
    }
    {
      RD_A(0, 0, 0); RD_B(0, 0);
      STG_B(1, 15, 65536);
      PH_TAIL(0); barx();
      RD_A(1, 0, 0);
      STG_A(0, 15, 65536); STG_A(1, 15, 65536);
      PH_TAIL(1); barx();
      RD_A(0, 1, 0); RD_B(1, 0);
      PH_TAIL(0); barx();
      RD_A(1, 1, 0);
      PH_TAIL(1);
      asm volatile("s_waitcnt vmcnt(0)" ::: "memory");
      barx();
      RD_A(0, 0, 65536); RD_B(0, 65536);
      PH_TAIL(0); barx();
      RD_A(1, 0, 65536);
      PH_TAIL(1); barx();
      RD_A(0, 1, 65536); RD_B(1, 65536);
      PH_TAIL(0); barx();
      RD_A(1, 1, 65536);
      PH_TAIL(1);
    }

    #pragma unroll
    for (int mf = 0; mf < 8; ++mf) {
      int lr = wm * 128 + mf * 16 + kg * 4;
      #pragma unroll
      for (int np = 0; np < 2; ++np) {
        int col = n0 + (2 * wn + np) * 16 + r16;
        #pragma unroll
        for (int r = 0; r < 4; ++r) {
          int slot = slot0 + lr + r;
          if (slot < send) {
            float g = acc[mf][2 * np][r];
            float u = acc[mf][2 * np + 1][r];
            float y = (g / (1.f + __expf(-g))) * u;
            act[(size_t)slot * ID + col] = f2bf(y);
          }
        }
      }
    }
  }
}

// ---------------- GEMM2 v15: BM=128, BN=64, (256,3) — minimizes makespan model ----
// makespan = ceil(tiles/(256*bpc)) * bpc * tile_work: BN64/bpc3 = 4.5tau vs 6tau.
__global__ __launch_bounds__(256, 3) void k_gemm2(
    const unsigned short* __restrict__ act,   // [TOK][ID] bf16
    const unsigned short* __restrict__ dT,    // [NE][HD][ID] bf16
    const int* __restrict__ meta,
    const int* __restrict__ perm,
    float* __restrict__ out) {                // [TOK][HD] f32
  __shared__ unsigned short As[128 * 64];     // 16 KB
  __shared__ unsigned short Bs[64 * 64];      // 8 KB
  int offs[5];
  #pragma unroll
  for (int i = 0; i < 5; ++i) offs[i] = meta[i];
  // chunked XCD swizzle: 2096 = 8*262; 16 ny of one mt land consecutively per XCD.
  int bid = blockIdx.x;
  int logical = (bid & 7) * (NT2 / 8) + (bid >> 3);
  int mt = logical >> 4;
  int nyy = logical & 15;
  int e = -1, mloc = 0, base = 0;
  #pragma unroll
  for (int ee = 0; ee < 4; ++ee) {
    int tiles = (offs[ee + 1] - offs[ee] + 127) >> 7;
    if (e < 0 && mt < base + tiles) { e = ee; mloc = mt - base; }
    base += tiles;
  }
  if (e < 0) return;
  int slot0 = offs[e] + (mloc << 7);
  int send = offs[e + 1];
  int tid = threadIdx.x;
  int n0 = nyy << 6;                          // 64-wide N panel
  const unsigned short* dbase = dT + (size_t)e * HD * ID;
  const unsigned short* ap[4];
  const unsigned short* bp[2];
  int wofsA[4], wofsB[2];
  #pragma unroll
  for (int it = 0; it < 4; ++it) {
    int b = (tid << 4) + (it << 12);          // byte in 16KB A tile
    int row = b >> 7;                         // 0..127
    int kob = b & 127;
    int slot = slot0 + row;
    int s2 = slot < send ? slot : slot0;
    ap[it] = act + (size_t)s2 * ID + (kob >> 1);
    wofsA[it] = row * 64 + ((kob ^ ((row & 7) << 4)) >> 1);
  }
  #pragma unroll
  for (int it = 0; it < 2; ++it) {
    int b = (tid << 4) + (it << 12);          // byte in 8KB B tile
    int row = b >> 7;                         // 0..63
    int kob = b & 127;
    bp[it] = dbase + (size_t)(n0 + row) * ID + (kob >> 1);
    wofsB[it] = row * 64 + ((kob ^ ((row & 7) << 4)) >> 1);
  }
  int lane = tid & 63, wid = tid >> 6;
  int wm = wid >> 1, wn = wid & 1;            // 2M x 2N; wave output 64x32
  int r16 = lane & 15, kg = lane >> 4;
  f32x4 acc[4][2];
  #pragma unroll
  for (int m = 0; m < 4; ++m)
    #pragma unroll
    for (int n = 0; n < 2; ++n) acc[m][n] = (f32x4){0.f, 0.f, 0.f, 0.f};

  bf16x8 sa[4], sb[2];
  #pragma unroll
  for (int it = 0; it < 4; ++it) sa[it] = *(const bf16x8*)(ap[it]);
  #pragma unroll
  for (int it = 0; it < 2; ++it) sb[it] = *(const bf16x8*)(bp[it]);
  for (int kt = 0; kt < ID / 64; ++kt) {
    __syncthreads();
    #pragma unroll
    for (int it = 0; it < 4; ++it) *(bf16x8*)(As + wofsA[it]) = sa[it];
    #pragma unroll
    for (int it = 0; it < 2; ++it) *(bf16x8*)(Bs + wofsB[it]) = sb[it];
    __syncthreads();
    if (kt < ID / 64 - 1) {
      int ko = (kt + 1) << 6;
      #pragma unroll
      for (int it = 0; it < 4; ++it) sa[it] = *(const bf16x8*)(ap[it] + ko);
      #pragma unroll
      for (int it = 0; it < 2; ++it) sb[it] = *(const bf16x8*)(bp[it] + ko);
    }
    #pragma unroll
    for (int kk = 0; kk < 2; ++kk) {
      bf16x8 fa[4], fb[2];
      #pragma unroll
      for (int m = 0; m < 4; ++m) {
        int row = (wm << 6) + (m << 4) + r16;
        int kob = (kk << 6) + (kg << 4);
        fa[m] = *(const bf16x8*)(As + row * 64 + ((kob ^ ((row & 7) << 4)) >> 1));
      }
      #pragma unroll
      for (int n = 0; n < 2; ++n) {
        int row = (wn << 5) + (n << 4) + r16;
        int kob = (kk << 6) + (kg << 4);
        fb[n] = *(const bf16x8*)(Bs + row * 64 + ((kob ^ ((row & 7) << 4)) >> 1));
      }
      #pragma unroll
      for (int m = 0; m < 4; ++m)
        #pragma unroll
        for (int n = 0; n < 2; ++n)
          acc[m][n] = MFMA16(fa[m], fb[n], acc[m][n], 0, 0, 0);
    }
  }
  // epilogue: scatter rows to out[perm[slot]]
  #pragma unroll
  for (int m = 0; m < 4; ++m) {
    int lr = (wm << 6) + (m << 4) + (kg << 2);
    int pr4[4];
    #pragma unroll
    for (int r = 0; r < 4; ++r) {
      int slot = slot0 + lr + r;
      pr4[r] = slot < send ? perm[slot] : -1;
    }
    #pragma unroll
    for (int n = 0; n < 2; ++n) {
      int col = n0 + (wn << 5) + (n << 4) + r16;
      #pragma unroll
      for (int r = 0; r < 4; ++r) {
        if (pr4[r] >= 0) out[(size_t)pr4[r] * HD + col] = acc[m][n][r];
      }
    }
  }
}

extern "C" void kernel_launch(void* const* d_in, const int* in_sizes, int n_in,
                              void* d_out, int out_size, void* d_ws, size_t ws_size,
                              hipStream_t stream) {
  const float* hs = (const float*)d_in[0];
  const float* gw = (const float*)d_in[1];
  const float* uw = (const float*)d_in[2];
  const float* dw = (const float*)d_in[3];
  const int* ids = (const int*)d_in[4];
  float* out = (float*)d_out;

  char* w = (char*)d_ws;
  size_t o = 0;
  int* meta = (int*)(w + o); o += 64;
  int* ctrs = (int*)(w + o); o += 64;
  int* perm = (int*)(w + o); o += (size_t)TOK * 4;
  o = (o + 255) & ~(size_t)255;
  unsigned short* hid = (unsigned short*)(w + o); o += (size_t)TOK * HD * 2;
  unsigned short* gT  = (unsigned short*)(w + o); o += (size_t)NE * ID * HD * 2;
  unsigned short* uT  = (unsigned short*)(w + o); o += (size_t)NE * ID * HD * 2;
  unsigned short* dT  = (unsigned short*)(w + o); o += (size_t)NE * ID * HD * 2;
  unsigned short* actb = (unsigned short*)(w + o); o += (size_t)TOK * ID * 2;
  // requires ws_size >= ~268.6 MB

  hipFuncSetAttribute((const void*)k_gemm1,
                      hipFuncAttributeMaxDynamicSharedMemorySize, 131072);

  hipLaunchKernelGGL(k_route0, dim3(1), dim3(256), 0, stream, ids, meta, ctrs);
  hipLaunchKernelGGL(k_route1, dim3(TOK / 256), dim3(256), 0, stream, ids, meta, perm);
  hipLaunchKernelGGL(k_pre, dim3(1024, 20), dim3(256), 0, stream,
                     gw, uw, dw, hs, gT, uT, dT, hid);
  hipLaunchKernelGGL(k_gemm1, dim3(256), dim3(512), 131072, stream,
                     hid, gT, uT, meta, perm, actb, &ctrs[0]);
  hipLaunchKernelGGL(k_gemm2, dim3(NT2), dim3(256), 0, stream,
                     actb, dT, meta, perm, out);
}

// Round 16
// 631.690 us; speedup vs baseline: 1.0346x; 1.0346x over previous
//
#include <hip/hip_runtime.h>

#define TOK    16384
#define HD     1024
#define ID     4096
#define NE     4
#define MAXMT  131   // worst-case M-tiles at BM=128
#define MAXMT2 67    // worst-case M-tiles at BM=256 (gemm1)
#define NKT    (HD / 64)   // 16 K-tiles for gemm1
#define NT1    (MAXMT2 * 32)   // gemm1 tile-id bound

typedef __attribute__((ext_vector_type(4))) float f32x4;
typedef __attribute__((ext_vector_type(8))) short bf16x8;
typedef unsigned int u32;

static __device__ __forceinline__ unsigned short f2bf(float f) {
  unsigned u = __float_as_uint(f);
  u += 0x7FFFu + ((u >> 16) & 1u);   // RNE
  return (unsigned short)(u >> 16);
}

static __device__ __forceinline__ void gl16(const void* g, void* l) {
  __builtin_amdgcn_global_load_lds((const __attribute__((address_space(1))) u32*)g,
                                   (__attribute__((address_space(3))) u32*)l, 16, 0, 0);
}

static __device__ __forceinline__ void barx() {
  asm volatile("" ::: "memory");
  __builtin_amdgcn_s_barrier();
  asm volatile("" ::: "memory");
}

// ---------------- routing (+ persistent-counter reset each call) ----------------
__global__ void k_route0(const int* __restrict__ ids, int* __restrict__ meta,
                         int* __restrict__ ctrs) {
  __shared__ int cnt[4];
  int t = threadIdx.x;
  if (t < 4) cnt[t] = 0;
  __syncthreads();
  int l0 = 0, l1 = 0, l2 = 0, l3 = 0;
  for (int i = t; i < TOK; i += 256) {
    int e = ids[i] & 3;
    l0 += (e == 0); l1 += (e == 1); l2 += (e == 2); l3 += (e == 3);
  }
  atomicAdd(&cnt[0], l0); atomicAdd(&cnt[1], l1);
  atomicAdd(&cnt[2], l2); atomicAdd(&cnt[3], l3);
  __syncthreads();
  if (t == 0) {
    int o = 0;
    for (int e = 0; e < 4; ++e) { meta[e] = o; meta[8 + e] = o; o += cnt[e]; }
    meta[4] = o;
    ctrs[0] = 0;   // gemm1 work-steal counter
  }
}

__global__ void k_route1(const int* __restrict__ ids, int* __restrict__ meta,
                         int* __restrict__ perm) {
  int i = blockIdx.x * 256 + threadIdx.x;
  if (i < TOK) {
    int e = ids[i] & 3;
    int s = atomicAdd(&meta[8 + e], 1);
    perm[s] = i;
  }
}

// ------- fused pre-pass: z 0..11 weight transposes, z 12..19 hid f32->bf16 -------
__global__ void k_pre(const float* __restrict__ gw, const float* __restrict__ uw,
                      const float* __restrict__ dw, const float* __restrict__ hs,
                      unsigned short* __restrict__ gT, unsigned short* __restrict__ uT,
                      unsigned short* __restrict__ dT, unsigned short* __restrict__ hid) {
  int z = blockIdx.y;
  int t = threadIdx.x;
  if (z >= 12) {
    int i = ((z - 12) * 1024 + blockIdx.x) * 256 + t;   // vec8 index
    const f32x4* p = (const f32x4*)(hs + ((size_t)i << 3));
    f32x4 a = p[0], b = p[1];
    union { unsigned short u[8]; uint4 q; } o;
    o.u[0] = f2bf(a.x); o.u[1] = f2bf(a.y); o.u[2] = f2bf(a.z); o.u[3] = f2bf(a.w);
    o.u[4] = f2bf(b.x); o.u[5] = f2bf(b.y); o.u[6] = f2bf(b.z); o.u[7] = f2bf(b.w);
    *(uint4*)(hid + ((size_t)i << 3)) = o.q;
    return;
  }
  __shared__ float tile[64][65];
  const float* s; unsigned short* d; int R, C, lg;
  if (z < 8) {
    R = HD; C = ID; lg = 6;
    int m = z & 3;
    if (z < 4) { s = gw + (size_t)m * R * C; d = gT + (size_t)m * R * C; }
    else       { s = uw + (size_t)m * R * C; d = uT + (size_t)m * R * C; }
  } else {
    R = ID; C = HD; lg = 4;
    int m = z - 8;
    s = dw + (size_t)m * R * C; d = dT + (size_t)m * R * C;
  }
  int bx = blockIdx.x;
  int tx = bx & ((1 << lg) - 1), ty = bx >> lg;
  int r0 = ty << 6, c0 = tx << 6;
  int lr = t >> 4, lc = (t & 15) << 2;
  #pragma unroll
  for (int it = 0; it < 4; ++it) {
    int r = lr + (it << 4);
    f32x4 v = *(const f32x4*)(s + (size_t)(r0 + r) * C + c0 + lc);
    tile[r][lc] = v.x; tile[r][lc + 1] = v.y; tile[r][lc + 2] = v.z; tile[r][lc + 3] = v.w;
  }
  __syncthreads();
  int c = t >> 2, rb = (t & 3) << 4;
  union { unsigned short u[16]; uint4 q[2]; } o;
  #pragma unroll
  for (int j = 0; j < 16; ++j) o.u[j] = f2bf(tile[rb + j][c]);
  uint4* dp = (uint4*)(d + (size_t)(c0 + c) * R + r0 + rb);
  dp[0] = o.q[0]; dp[1] = o.q[1];
}

// ---------------- GEMM1: round-3 body in persistent work-steal loop (round-13/14) ----
#define MFMA16 __builtin_amdgcn_mfma_f32_16x16x32_bf16

#define RD_A(MH, KX, D) { _Pragma("unroll") for (int m = 0; m < 4; ++m) \
  fa[m] = *(const bf16x8*)(smem + (D) + ((offA[m] + (MH) * 8192) ^ ((KX) << 6))); }
#define RD_B(KX, D) { _Pragma("unroll") for (int n = 0; n < 4; ++n) \
  fb[n] = *(const bf16x8*)(smem + (D) + (offB[n] ^ ((KX) << 6))); }
#define STG_A(HH, TILE, D) { _Pragma("unroll") for (int j = (HH) * 2; j < (HH) * 2 + 2; ++j) \
  gl16(srcA[j] + (TILE) * 64, smem + (D) + dstA[j]); }
#define STG_B(HH, TILE, D) { _Pragma("unroll") for (int j = (HH) * 2; j < (HH) * 2 + 2; ++j) \
  gl16(srcB[j] + (TILE) * 64, smem + (D) + dstB[j]); }
#define PH_TAIL(MH) barx(); \
  asm volatile("s_waitcnt lgkmcnt(0)" ::: "memory"); \
  __builtin_amdgcn_sched_barrier(0); \
  __builtin_amdgcn_s_setprio(1); \
  { _Pragma("unroll") for (int m = 0; m < 4; ++m) \
    _Pragma("unroll") for (int n = 0; n < 4; ++n) \
      acc[(MH) * 4 + m][n] = MFMA16(fa[m], fb[n], acc[(MH) * 4 + m][n], 0, 0, 0); } \
  __builtin_amdgcn_s_setprio(0)

__global__ __launch_bounds__(512, 2) void k_gemm1(
    const unsigned short* __restrict__ hid,   // [TOK][HD] bf16
    const unsigned short* __restrict__ gT,    // [NE][ID][HD] bf16
    const unsigned short* __restrict__ uT,    // [NE][ID][HD] bf16
    const int* __restrict__ meta,
    const int* __restrict__ perm,
    unsigned short* __restrict__ act,         // [TOK][ID] bf16, slot-ordered
    int* ctr) {
  extern __shared__ __align__(16) char smem[];   // 2 dbuf x (A 32K | B 32K)
  __shared__ int s_t;
  int offs[5];
  #pragma unroll
  for (int i = 0; i < 5; ++i) offs[i] = meta[i];
  int tid = threadIdx.x, lane = tid & 63, wid = tid >> 6;

  // ---- tile-invariant setup ----
  int rsub = lane >> 3;                       // 0..7
  int ke = ((lane & 7) ^ rsub) << 3;          // element offset within 64-wide k-chunk
  int dstA[4], dstB[4];
  #pragma unroll
  for (int j = 0; j < 4; ++j) {
    dstA[j] = j * 8192 + wid * 1024;
    dstB[j] = 32768 + j * 8192 + wid * 1024;
  }
  int wm = wid >> 2, wn = wid & 3;            // 2M x 4N waves
  int r16 = lane & 15, kg = lane >> 4;
  int offA[4], offB[4];
  #pragma unroll
  for (int m = 0; m < 4; ++m) {
    int row = wm * 128 + m * 16 + r16;
    offA[m] = row * 128 + ((kg << 4) ^ ((row & 7) << 4));
  }
  #pragma unroll
  for (int n = 0; n < 4; ++n) {
    int row = wn * 64 + n * 16 + r16;
    offB[n] = 32768 + row * 128 + ((kg << 4) ^ ((row & 7) << 4));
  }
  bf16x8 fa[4], fb[4];

  for (;;) {
    __syncthreads();                          // broadcast slot + cross-tile LDS fence
    if (tid == 0) s_t = atomicAdd(ctr, 1);
    __syncthreads();
    int tt = s_t;
    if (tt >= NT1) break;
    int mt = tt >> 5;
    int ny = tt & 31;
    int e = -1, mloc = 0, base = 0;
    #pragma unroll
    for (int ee = 0; ee < 4; ++ee) {
      int tiles = (offs[ee + 1] - offs[ee] + 255) >> 8;
      if (e < 0 && mt < base + tiles) { e = ee; mloc = mt - base; }
      base += tiles;
    }
    if (e < 0) continue;
    int slot0 = offs[e] + (mloc << 8);
    int send = offs[e + 1];
    int n0 = ny << 7;

    const unsigned short* srcA[4];
    const unsigned short* srcB[4];
    const unsigned short* gb = gT + (size_t)e * ID * HD;
    const unsigned short* ub = uT + (size_t)e * ID * HD;
    #pragma unroll
    for (int j = 0; j < 4; ++j) {
      int r = j * 64 + wid * 8 + rsub;        // A tile row 0..255
      int slot = slot0 + r;
      int pr = perm[slot < send ? slot : slot0];
      srcA[j] = hid + (size_t)pr * HD + ke;
      int s = r >> 4;                         // subtile: even->G, odd->U
      int grow = n0 + ((s >> 1) << 4) + (r & 15);
      srcB[j] = ((s & 1) ? ub : gb) + (size_t)grow * HD + ke;
    }

    f32x4 acc[8][4];
    #pragma unroll
    for (int m = 0; m < 8; ++m)
      #pragma unroll
      for (int n = 0; n < 4; ++n) acc[m][n] = (f32x4){0.f, 0.f, 0.f, 0.f};

    STG_B(0, 0, 0);
    STG_A(0, 0, 0); STG_A(1, 0, 0);
    STG_B(1, 0, 0);
    STG_B(0, 1, 65536);
    asm volatile("s_waitcnt vmcnt(2)" ::: "memory");
    barx();

    #pragma unroll 1
    for (int i = 0; i < NKT / 2 - 1; ++i) {
      int t1 = 2 * i + 1, t2 = 2 * i + 2, t3 = 2 * i + 3;
      RD_A(0, 0, 0); RD_B(0, 0);
      STG_B(1, t1, 65536);
      PH_TAIL(0); barx();
      RD_A(1, 0, 0);
      STG_A(0, t1, 65536); STG_A(1, t1, 65536);
      PH_TAIL(1); barx();
      RD_A(0, 1, 0); RD_B(1, 0);
      PH_TAIL(0); barx();
      RD_A(1, 1, 0);
      STG_B(0, t2, 0);
      PH_TAIL(1);
      asm volatile("s_waitcnt vmcnt(2)" ::: "memory");
      barx();
      RD_A(0, 0, 65536); RD_B(0, 65536);
      STG_A(0, t2, 0); STG_A(1, t2, 0);
      PH_TAIL(0); barx();
      RD_A(1, 0, 65536);
      STG_B(1, t2, 0);
      PH_TAIL(1); barx();
      RD_A(0, 1, 65536); RD_B(1, 65536);
      PH_TAIL(0); barx();
      RD_A(1, 1, 65536);
      STG_B(0, t3, 65536);
      PH_TAIL(1);
      asm volatile("s_waitcnt vmcnt(2)" ::: "memory");
      barx();
    }
    {
      RD_A(0, 0, 0); RD_B(0, 0);
      STG_B(1, 15, 65536);
      PH_TAIL(0); barx();
      RD_A(1, 0, 0);
      STG_A(0, 15, 65536); STG_A(1, 15, 65536);
      PH_TAIL(1); barx();
      RD_A(0, 1, 0); RD_B(1, 0);
      PH_TAIL(0); barx();
      RD_A(1, 1, 0);
      PH_TAIL(1);
      asm volatile("s_waitcnt vmcnt(0)" ::: "memory");
      barx();
      RD_A(0, 0, 65536); RD_B(0, 65536);
      PH_TAIL(0); barx();
      RD_A(1, 0, 65536);
      PH_TAIL(1); barx();
      RD_A(0, 1, 65536); RD_B(1, 65536);
      PH_TAIL(0); barx();
      RD_A(1, 1, 65536);
      PH_TAIL(1);
    }

    #pragma unroll
    for (int mf = 0; mf < 8; ++mf) {
      int lr = wm * 128 + mf * 16 + kg * 4;
      #pragma unroll
      for (int np = 0; np < 2; ++np) {
        int col = n0 + (2 * wn + np) * 16 + r16;
        #pragma unroll
        for (int r = 0; r < 4; ++r) {
          int slot = slot0 + lr + r;
          if (slot < send) {
            float g = acc[mf][2 * np][r];
            float u = acc[mf][2 * np + 1][r];
            float y = (g / (1.f + __expf(-g))) * u;
            act[(size_t)slot * ID + col] = f2bf(y);
          }
        }
      }
    }
  }
}

// ---------------- GEMM2 (round-11 static, chunked XCD swizzle, (256,2)) ----------------
__global__ __launch_bounds__(256, 2) void k_gemm2(
    const unsigned short* __restrict__ act,   // [TOK][ID] bf16
    const unsigned short* __restrict__ dT,    // [NE][HD][ID] bf16
    const int* __restrict__ meta,
    const int* __restrict__ perm,
    float* __restrict__ out) {                // [TOK][HD] f32
  __shared__ unsigned short As[128 * 64];
  __shared__ unsigned short Bs[128 * 64];
  int offs[5];
  #pragma unroll
  for (int i = 0; i < 5; ++i) offs[i] = meta[i];
  // chunked XCD swizzle: 1048 = 8*131; 8 ny of one mt land on one XCD.
  int bid = blockIdx.x;
  int logical = (bid & 7) * (MAXMT * 8 / 8) + (bid >> 3);
  int mt = logical >> 3;
  int nyy = logical & 7;
  int e = -1, mloc = 0, base = 0;
  #pragma unroll
  for (int ee = 0; ee < 4; ++ee) {
    int tiles = (offs[ee + 1] - offs[ee] + 127) >> 7;
    if (e < 0 && mt < base + tiles) { e = ee; mloc = mt - base; }
    base += tiles;
  }
  if (e < 0) return;
  int slot0 = offs[e] + (mloc << 7);
  int send = offs[e + 1];
  int tid = threadIdx.x;
  int n0 = nyy << 7;
  const unsigned short* dbase = dT + (size_t)e * HD * ID;
  const unsigned short* ap[4];
  const unsigned short* bp[4];
  int wofs[4];
  #pragma unroll
  for (int it = 0; it < 4; ++it) {
    int b = (tid << 4) + (it << 12);
    int row = b >> 7;
    int kob = b & 127;
    int slot = slot0 + row;
    int s2 = slot < send ? slot : slot0;
    ap[it] = act + (size_t)s2 * ID + (kob >> 1);
    bp[it] = dbase + (size_t)(n0 + row) * ID + (kob >> 1);
    wofs[it] = row * 64 + ((kob ^ ((row & 7) << 4)) >> 1);
  }
  int lane = tid & 63, wid = tid >> 6;
  int wm = wid >> 1, wn = wid & 1;
  int r16 = lane & 15, kg = lane >> 4;
  f32x4 zero = {0.f, 0.f, 0.f, 0.f};
  f32x4 acc[4][4];
  #pragma unroll
  for (int m = 0; m < 4; ++m)
    #pragma unroll
    for (int n = 0; n < 4; ++n) acc[m][n] = zero;

  bf16x8 sa[4], sb[4];
  #pragma unroll
  for (int it = 0; it < 4; ++it) {
    sa[it] = *(const bf16x8*)(ap[it]);
    sb[it] = *(const bf16x8*)(bp[it]);
  }
  for (int kt = 0; kt < ID / 64; ++kt) {
    __syncthreads();
    #pragma unroll
    for (int it = 0; it < 4; ++it) {
      *(bf16x8*)(As + wofs[it]) = sa[it];
      *(bf16x8*)(Bs + wofs[it]) = sb[it];
    }
    __syncthreads();
    if (kt < ID / 64 - 1) {
      int ko = (kt + 1) << 6;
      #pragma unroll
      for (int it = 0; it < 4; ++it) {
        sa[it] = *(const bf16x8*)(ap[it] + ko);
        sb[it] = *(const bf16x8*)(bp[it] + ko);
      }
    }
    #pragma unroll
    for (int kk = 0; kk < 2; ++kk) {
      bf16x8 fa[4], fb[4];
      #pragma unroll
      for (int m = 0; m < 4; ++m) {
        int row = (wm << 6) + (m << 4) + r16;
        int kob = (kk << 6) + (kg << 4);
        fa[m] = *(const bf16x8*)(As + row * 64 + ((kob ^ ((row & 7) << 4)) >> 1));
      }
      #pragma unroll
      for (int n = 0; n < 4; ++n) {
        int row = (wn << 6) + (n << 4) + r16;
        int kob = (kk << 6) + (kg << 4);
        fb[n] = *(const bf16x8*)(Bs + row * 64 + ((kob ^ ((row & 7) << 4)) >> 1));
      }
      #pragma unroll
      for (int m = 0; m < 4; ++m)
        #pragma unroll
        for (int n = 0; n < 4; ++n)
          acc[m][n] = __builtin_amdgcn_mfma_f32_16x16x32_bf16(fa[m], fb[n], acc[m][n], 0, 0, 0);
    }
  }
  #pragma unroll
  for (int m = 0; m < 4; ++m) {
    int lr = (wm << 6) + (m << 4) + (kg << 2);
    int pr4[4];
    #pragma unroll
    for (int r = 0; r < 4; ++r) {
      int slot = slot0 + lr + r;
      pr4[r] = slot < send ? perm[slot] : -1;
    }
    #pragma unroll
    for (int n = 0; n < 4; ++n) {
      int col = n0 + (wn << 6) + (n << 4) + r16;
      #pragma unroll
      for (int r = 0; r < 4; ++r) {
        if (pr4[r] >= 0) out[(size_t)pr4[r] * HD + col] = acc[m][n][r];
      }
    }
  }
}

extern "C" void kernel_launch(void* const* d_in, const int* in_sizes, int n_in,
                              void* d_out, int out_size, void* d_ws, size_t ws_size,
                              hipStream_t stream) {
  const float* hs = (const float*)d_in[0];
  const float* gw = (const float*)d_in[1];
  const float* uw = (const float*)d_in[2];
  const float* dw = (const float*)d_in[3];
  const int* ids = (const int*)d_in[4];
  float* out = (float*)d_out;

  char* w = (char*)d_ws;
  size_t o = 0;
  int* meta = (int*)(w + o); o += 64;
  int* ctrs = (int*)(w + o); o += 64;
  int* perm = (int*)(w + o); o += (size_t)TOK * 4;
  o = (o + 255) & ~(size_t)255;
  unsigned short* hid = (unsigned short*)(w + o); o += (size_t)TOK * HD * 2;
  unsigned short* gT  = (unsigned short*)(w + o); o += (size_t)NE * ID * HD * 2;
  unsigned short* uT  = (unsigned short*)(w + o); o += (size_t)NE * ID * HD * 2;
  unsigned short* dT  = (unsigned short*)(w + o); o += (size_t)NE * ID * HD * 2;
  unsigned short* actb = (unsigned short*)(w + o); o += (size_t)TOK * ID * 2;
  // requires ws_size >= ~268.6 MB

  hipFuncSetAttribute((const void*)k_gemm1,
                      hipFuncAttributeMaxDynamicSharedMemorySize, 131072);

  hipLaunchKernelGGL(k_route0, dim3(1), dim3(256), 0, stream, ids, meta, ctrs);
  hipLaunchKernelGGL(k_route1, dim3(TOK / 256), dim3(256), 0, stream, ids, meta, perm);
  hipLaunchKernelGGL(k_pre, dim3(1024, 20), dim3(256), 0, stream,
                     gw, uw, dw, hs, gT, uT, dT, hid);
  hipLaunchKernelGGL(k_gemm1, dim3(256), dim3(512), 131072, stream,
                     hid, gT, uT, meta, perm, actb, &ctrs[0]);
  hipLaunchKernelGGL(k_gemm2, dim3(MAXMT * 8), dim3(256), 0, stream,
                     actb, dT, meta, perm, out);
}